// Round 1
// baseline (75.415 us; speedup 1.0000x reference)
//
#include <hip/hip_runtime.h>
#include <stdint.h>

#define B 8
#define H 192
#define W 192
#define NPIX (B * H * W) /* 294912 */
#define NROWS (B * H)    /* 1536 */
#define INFF 1e12f

#define SPLITS 8         /* row-group blocks per batch image */
#define RPB (H / SPLITS) /* 24 rows per block */
#define SLOTS 4          /* rows processed concurrently (768 = 4*192) */
#define ITERS (RPB / SLOTS) /* 6 */

// ---------------------------------------------------------------------------
// Nearest set bit (clamped to 255) from position h in a 192-bit column bitset
// (s2:s1:s0), inclusive of h. Proven exact in the previous session (absmax 0).
// ---------------------------------------------------------------------------
__device__ __forceinline__ int hi_pos(uint64_t w0, uint64_t w1, uint64_t w2) {
  if (w2) return 191 - __builtin_clzll(w2);
  if (w1) return 127 - __builtin_clzll(w1);
  if (w0) return 63 - __builtin_clzll(w0);
  return -255;  // none below -> distance >= 255
}
__device__ __forceinline__ int lo_pos(uint64_t w0, uint64_t w1, uint64_t w2) {
  if (w0) return __builtin_ctzll(w0);
  if (w1) return 64 + __builtin_ctzll(w1);
  if (w2) return 128 + __builtin_ctzll(w2);
  return 447;  // none above -> distance >= 255
}
__device__ __forceinline__ int nearest_dist(uint64_t s0, uint64_t s1,
                                            uint64_t s2, int h) {
  int k = h >> 6, r = h & 63;
  uint64_t keepL = (2ull << r) - 1;  // bits 0..r (r=63 -> all ones)
  uint64_t b0 = s0, b1 = s1, b2 = s2;
  if (k == 0) { b0 &= keepL; b1 = 0; b2 = 0; }
  else if (k == 1) { b1 &= keepL; b2 = 0; }
  else { b2 &= keepL; }
  int dbelow = h - hi_pos(b0, b1, b2);
  uint64_t keepU = (~0ull) << r;  // bits r..63
  uint64_t a0 = s0, a1 = s1, a2 = s2;
  if (k == 0) { a0 &= keepU; }
  else if (k == 1) { a0 = 0; a1 &= keepU; }
  else { a0 = 0; a1 = 0; a2 &= keepU; }
  int dabove = lo_pos(a0, a1, a2) - h;
  return min(min(dbelow, dabove), 255);
}

// ---------------------------------------------------------------------------
// Fused K1+K2. One block per (batch, 24-row group): 64 blocks x 768 threads.
//
// Phase 1: rebuild ALL 192 column bitmasks of this batch in LDS (9 KB).
//   576 threads, thread (k,w) walks rows 64k..64k+63 of column w with
//   COALESCED loads (lanes = consecutive w -> contiguous 256B per wave;
//   this fixes the old col_mask's stride-768B uncoalesced pattern) and
//   builds its u64 word with constant-shift ORs. Duplicated 8x per batch
//   but the 288 KB image is L2-resident, so HBM fetch stays ~one pass.
//
// Phase 2: the proven row pass, 4 rows in flight (slot = t/192, w = t%192;
//   slot boundaries align with wave boundaries since 64 | 192). Each thread
//   loads its column's 6 mask words from LDS ONCE into registers and reuses
//   them for all 6 row iterations. Row math, packed-u8 LDS exchange,
//   early-exit horizontal scan, and the per-row reduction tree (64-wide
//   shuffle + 3-word combine -> partial[bh]) are bit-identical to the
//   previous 65 us kernel, so the final sum order is unchanged (absmax 0).
//
// NOTE (prev session lesson): no __threadfence / last-block patterns —
// device-scope fences on 8 non-coherent XCD L2s cost ~30 us. Cross-block
// visibility of `partial` comes free at the kernel boundary.
// ---------------------------------------------------------------------------
__global__ __launch_bounds__(768) void fused_pass(
    const float* __restrict__ pred, const float* __restrict__ targ,
    float* __restrict__ partial) {
  int blk = blockIdx.x;
  int b = blk >> 3, rg = blk & 7;  // SPLITS == 8
  int row0 = rg * RPB;
  int t = threadIdx.x;

  __shared__ uint64_t cm[2][3][W];  // [pred/targ][word][column]
  __shared__ uint32_t sm[SLOTS][W];
  __shared__ float wsum[SLOTS][3];

  // ---- phase 1: column masks for the whole batch image ----
  if (t < 3 * W) {
    int k = t / W, w = t - k * W;
    const float* pb = pred + b * H * W;
    const float* tb = targ + b * H * W;
    int base = (k << 6) * W + w;
    uint64_t pw = 0, qw = 0;
#pragma unroll 16
    for (int j = 0; j < 64; ++j) {
      pw |= (uint64_t)(pb[base + j * W] > 0.0f) << j;  // sigmoid(x)>0.5 <=> x>0
      qw |= (uint64_t)(tb[base + j * W] > 0.5f) << j;
    }
    cm[0][k][w] = pw;
    cm[1][k][w] = qw;
  }
  __syncthreads();

  // ---- phase 2: row pass, 4 rows per iteration ----
  int slot = t / W, w = t - slot * W;
  // column masks -> registers, once (consecutive-u64 LDS reads: conflict-free)
  uint64_t p0 = cm[0][0][w], p1 = cm[0][1][w], p2 = cm[0][2][w];
  uint64_t q0 = cm[1][0][w], q1 = cm[1][1][w], q2 = cm[1][2][w];

  for (int it = 0; it < ITERS; ++it) {
    int h = row0 + it * SLOTS + slot;
    int base = b * H * W + h * W;
    float xv = pred[base + w];  // coalesced: consecutive w per 192-group
    float tv = targ[base + w];

    int k = h >> 6, rb = h & 63;
    uint64_t pw = (k == 0) ? p0 : ((k == 1) ? p1 : p2);
    uint64_t qw = (k == 0) ? q0 : ((k == 1) ? q1 : q2);
    int mp = (int)((pw >> rb) & 1);  // == (xv > 0)
    int mt = (int)((qw >> rb) & 1);  // == (tv > 0.5)
    int sp = nearest_dist(mp ? ~p0 : p0, mp ? ~p1 : p1, mp ? ~p2 : p2, h);
    int st = nearest_dist(mt ? ~q0 : q0, mt ? ~q1 : q1, mt ? ~q2 : q2, h);
    int dFp = mp ? sp : 0, dTp = mp ? 0 : sp;
    int dFt = mt ? st : 0, dTt = mt ? 0 : st;
    uint32_t own = (uint32_t)dFp | ((uint32_t)dTp << 8) |
                   ((uint32_t)dFt << 16) | ((uint32_t)dTt << 24);
    sm[slot][w] = own;
    __syncthreads();  // S1: sm(it) visible

    int shp = (xv > 0.0f) ? 0 : 8;   // fg pixel needs fg-EDT field, else bg
    int sht = (tv > 0.5f) ? 16 : 24;
    int dp = (own >> shp) & 255;
    int dt = (own >> sht) & 255;
    float bp = (dp == 255) ? INFF : (float)(dp * dp);
    float bt = (dt == 255) ? INFF : (float)(dt * dt);
    for (int r = 1; r < W; ++r) {
      float rr = (float)(r * r);
      if (rr >= fmaxf(bp, bt)) break;  // farther q can't improve either min
      int ql = w - r, qr = w + r;
      if (ql >= 0) {
        uint32_t v = sm[slot][ql];
        int a = (v >> shp) & 255, c = (v >> sht) & 255;
        bp = fminf(bp, (a == 255) ? INFF : rr + (float)(a * a));
        bt = fminf(bt, (c == 255) ? INFF : rr + (float)(c * c));
      }
      if (qr < W) {
        uint32_t v = sm[slot][qr];
        int a = (v >> shp) & 255, c = (v >> sht) & 255;
        bp = fminf(bp, (a == 255) ? INFF : rr + (float)(a * a));
        bt = fminf(bt, (c == 255) ? INFF : rr + (float)(c * c));
      }
    }

    float p = 1.0f / (1.0f + __expf(-xv));
    float e = p - tv;
    float err = e * e;
    float pd = sqrtf(bp), td = sqrtf(bt);
    float s = pd + td;
    float term = err * (bp + bt) / (s * s);  // bp,bt >= 1 always: no 0/0

    // per-row reduction, identical tree to the previous kernel
    for (int off = 32; off > 0; off >>= 1) term += __shfl_down(term, off, 64);
    if ((w & 63) == 0) wsum[slot][w >> 6] = term;
    __syncthreads();  // S2: scan reads of sm(it) done; wsum(it) visible
    if (w == 0)
      partial[b * H + h] = wsum[slot][0] + wsum[slot][1] + wsum[slot][2];
    // next iteration's sm write is safe: every thread passed S2, so all
    // scan reads of sm(it) completed; wsum(it+1) writes happen only after
    // S1(it+1), which thread w==0 reaches only after its partial store.
  }
}

// ---------------------------------------------------------------------------
// K3 (unchanged, bit-identical): final reduce of 1536 row partials -> mean.
// Plain store to d_out (overwrites harness poison; no atomics, no fences).
// ---------------------------------------------------------------------------
__global__ __launch_bounds__(256) void reduce_pass(
    const float* __restrict__ partial, float* __restrict__ out) {
  int t = threadIdx.x;
  float s = 0.0f;
#pragma unroll
  for (int i = t; i < NROWS; i += 256) s += partial[i];
  for (int off = 32; off > 0; off >>= 1) s += __shfl_down(s, off, 64);
  __shared__ float ws[4];
  if ((t & 63) == 0) ws[t >> 6] = s;
  __syncthreads();
  if (t == 0) out[0] = (ws[0] + ws[1] + ws[2] + ws[3]) * (1.0f / (float)NPIX);
}

extern "C" void kernel_launch(void* const* d_in, const int* in_sizes, int n_in,
                              void* d_out, int out_size, void* d_ws,
                              size_t ws_size, hipStream_t stream) {
  const float* pred = (const float*)d_in[0];
  const float* targ = (const float*)d_in[1];
  float* out = (float*)d_out;
  float* partial = (float*)d_ws;  // NROWS f32 = 6 KB (masks no longer staged)

  fused_pass<<<B * SPLITS, 768, 0, stream>>>(pred, targ, partial);
  reduce_pass<<<1, 256, 0, stream>>>(partial, out);
}

// Round 2
// 67.480 us; speedup vs baseline: 1.1176x; 1.1176x over previous
//
#include <hip/hip_runtime.h>
#include <stdint.h>

#define B 8
#define H 192
#define W 192
#define NPIX (B * H * W) /* 294912 */
#define NROWS (B * H)    /* 1536 */
#define INFF 1e12f

#define SPLITS 32           /* row-group blocks per batch image */
#define RPB (H / SPLITS)    /* 6 rows per block */
#define SLOTS 3             /* rows processed concurrently (576 = 3*192) */
#define ITERS (RPB / SLOTS) /* 2 */
#define NTHR (SLOTS * W)    /* 576 threads = 9 waves */

// ---------------------------------------------------------------------------
// Nearest set bit (clamped to 255) from position h in a 192-bit column bitset
// (s2:s1:s0), inclusive of h. Proven exact (absmax 0 across sessions).
// ---------------------------------------------------------------------------
__device__ __forceinline__ int hi_pos(uint64_t w0, uint64_t w1, uint64_t w2) {
  if (w2) return 191 - __builtin_clzll(w2);
  if (w1) return 127 - __builtin_clzll(w1);
  if (w0) return 63 - __builtin_clzll(w0);
  return -255;  // none below -> distance >= 255
}
__device__ __forceinline__ int lo_pos(uint64_t w0, uint64_t w1, uint64_t w2) {
  if (w0) return __builtin_ctzll(w0);
  if (w1) return 64 + __builtin_ctzll(w1);
  if (w2) return 128 + __builtin_ctzll(w2);
  return 447;  // none above -> distance >= 255
}
__device__ __forceinline__ int nearest_dist(uint64_t s0, uint64_t s1,
                                            uint64_t s2, int h) {
  int k = h >> 6, r = h & 63;
  uint64_t keepL = (2ull << r) - 1;  // bits 0..r (r=63 -> all ones)
  uint64_t b0 = s0, b1 = s1, b2 = s2;
  if (k == 0) { b0 &= keepL; b1 = 0; b2 = 0; }
  else if (k == 1) { b1 &= keepL; b2 = 0; }
  else { b2 &= keepL; }
  int dbelow = h - hi_pos(b0, b1, b2);
  uint64_t keepU = (~0ull) << r;  // bits r..63
  uint64_t a0 = s0, a1 = s1, a2 = s2;
  if (k == 0) { a0 &= keepU; }
  else if (k == 1) { a0 = 0; a1 &= keepU; }
  else { a0 = 0; a1 = 0; a2 &= keepU; }
  int dabove = lo_pos(a0, a1, a2) - h;
  return min(min(dbelow, dabove), 255);
}

// ---------------------------------------------------------------------------
// Fused K1+K2, v2. R1 lesson: 64 blocks x 768 thr used only 64/256 CUs and
// serialized 6 iterations -> +10 us vs the 3-kernel baseline. v2 reshapes to
// 256 blocks x 576 thr (SPLITS=32): exactly 1 block/CU, ITERS=2, 9-wave
// syncs. Phase-1 rebuild redundancy = 256 x 576 KB ~= 147 MB of L2/L3 reads
// (~4 us aggregate) -- the price of killing the mask round-trip + a dispatch.
//
// Phase 1: 576 threads, thread (k=t/192, w=t%192) builds column-mask word k
//   of column w with 64 fully-coalesced row-walk loads (lanes = consecutive
//   w -> 256 B contiguous per wave-load).
// Phase 2: proven row pass, 3 rows in flight (slot = t/192, w = t%192; slot
//   boundary = wave boundary since 64 | 192). Column masks register-cached
//   across both iterations. Row math, packed-u8 LDS exchange, early-exit
//   scan, and the 64-lane shuffle + 3-word reduction tree are bit-identical
//   to the 64.9 us baseline -> absmax 0.
//
// NOTE: no __threadfence / last-block patterns -- device-scope fences on 8
// non-coherent XCD L2s cost ~30 us (prev session). Cross-block visibility
// of `partial` comes free at the kernel boundary.
// ---------------------------------------------------------------------------
__global__ __launch_bounds__(NTHR) void fused_pass(
    const float* __restrict__ pred, const float* __restrict__ targ,
    float* __restrict__ partial) {
  int blk = blockIdx.x;
  int b = blk >> 5, rg = blk & 31;  // SPLITS == 32
  int row0 = rg * RPB;
  int t = threadIdx.x;

  __shared__ uint64_t cm[2][3][W];  // [pred/targ][word][column]
  __shared__ uint32_t sm[SLOTS][W];
  __shared__ float wsum[SLOTS][3];

  // ---- phase 1: column masks for the whole batch image ----
  {
    int k = t / W, w = t - k * W;  // k in 0..2 (576 = 3*192 exactly)
    const float* pb = pred + b * H * W;
    const float* tb = targ + b * H * W;
    int base = (k << 6) * W + w;
    uint64_t pw = 0, qw = 0;
#pragma unroll 16
    for (int j = 0; j < 64; ++j) {
      pw |= (uint64_t)(pb[base + j * W] > 0.0f) << j;  // sigmoid(x)>0.5 <=> x>0
      qw |= (uint64_t)(tb[base + j * W] > 0.5f) << j;
    }
    cm[0][k][w] = pw;
    cm[1][k][w] = qw;
  }
  __syncthreads();

  // ---- phase 2: row pass, 3 rows per iteration, 2 iterations ----
  int slot = t / W, w = t - slot * W;
  // column masks -> registers, once (consecutive-u64 LDS reads: free 2-way)
  uint64_t p0 = cm[0][0][w], p1 = cm[0][1][w], p2 = cm[0][2][w];
  uint64_t q0 = cm[1][0][w], q1 = cm[1][1][w], q2 = cm[1][2][w];

  for (int it = 0; it < ITERS; ++it) {
    int h = row0 + it * SLOTS + slot;
    int base = b * H * W + h * W;
    float xv = pred[base + w];  // coalesced per 192-thread row group
    float tv = targ[base + w];

    int k = h >> 6, rb = h & 63;
    uint64_t pw = (k == 0) ? p0 : ((k == 1) ? p1 : p2);
    uint64_t qw = (k == 0) ? q0 : ((k == 1) ? q1 : q2);
    int mp = (int)((pw >> rb) & 1);  // == (xv > 0)
    int mt = (int)((qw >> rb) & 1);  // == (tv > 0.5)
    int sp = nearest_dist(mp ? ~p0 : p0, mp ? ~p1 : p1, mp ? ~p2 : p2, h);
    int st = nearest_dist(mt ? ~q0 : q0, mt ? ~q1 : q1, mt ? ~q2 : q2, h);
    int dFp = mp ? sp : 0, dTp = mp ? 0 : sp;
    int dFt = mt ? st : 0, dTt = mt ? 0 : st;
    uint32_t own = (uint32_t)dFp | ((uint32_t)dTp << 8) |
                   ((uint32_t)dFt << 16) | ((uint32_t)dTt << 24);
    sm[slot][w] = own;
    __syncthreads();  // S1: sm(it) visible

    int shp = (xv > 0.0f) ? 0 : 8;   // fg pixel needs fg-EDT field, else bg
    int sht = (tv > 0.5f) ? 16 : 24;
    int dp = (own >> shp) & 255;
    int dt = (own >> sht) & 255;
    float bp = (dp == 255) ? INFF : (float)(dp * dp);
    float bt = (dt == 255) ? INFF : (float)(dt * dt);
    for (int r = 1; r < W; ++r) {
      float rr = (float)(r * r);
      if (rr >= fmaxf(bp, bt)) break;  // farther q can't improve either min
      int ql = w - r, qr = w + r;
      if (ql >= 0) {
        uint32_t v = sm[slot][ql];
        int a = (v >> shp) & 255, c = (v >> sht) & 255;
        bp = fminf(bp, (a == 255) ? INFF : rr + (float)(a * a));
        bt = fminf(bt, (c == 255) ? INFF : rr + (float)(c * c));
      }
      if (qr < W) {
        uint32_t v = sm[slot][qr];
        int a = (v >> shp) & 255, c = (v >> sht) & 255;
        bp = fminf(bp, (a == 255) ? INFF : rr + (float)(a * a));
        bt = fminf(bt, (c == 255) ? INFF : rr + (float)(c * c));
      }
    }

    float p = 1.0f / (1.0f + __expf(-xv));
    float e = p - tv;
    float err = e * e;
    float pd = sqrtf(bp), td = sqrtf(bt);
    float s = pd + td;
    float term = err * (bp + bt) / (s * s);  // bp,bt >= 1 always: no 0/0

    // per-row reduction, identical tree to the 64.9 us baseline
    for (int off = 32; off > 0; off >>= 1) term += __shfl_down(term, off, 64);
    if ((w & 63) == 0) wsum[slot][w >> 6] = term;
    __syncthreads();  // S2: scan reads of sm(it) done; wsum(it) visible
    if (w == 0)
      partial[b * H + h] = wsum[slot][0] + wsum[slot][1] + wsum[slot][2];
    // next iteration's sm write is safe: every thread passed S2, so all
    // scan reads of sm(it) completed.
  }
}

// ---------------------------------------------------------------------------
// K3 (unchanged, bit-identical): final reduce of 1536 row partials -> mean.
// Plain store to d_out (overwrites harness poison; no atomics, no fences).
// ---------------------------------------------------------------------------
__global__ __launch_bounds__(256) void reduce_pass(
    const float* __restrict__ partial, float* __restrict__ out) {
  int t = threadIdx.x;
  float s = 0.0f;
#pragma unroll
  for (int i = t; i < NROWS; i += 256) s += partial[i];
  for (int off = 32; off > 0; off >>= 1) s += __shfl_down(s, off, 64);
  __shared__ float ws[4];
  if ((t & 63) == 0) ws[t >> 6] = s;
  __syncthreads();
  if (t == 0) out[0] = (ws[0] + ws[1] + ws[2] + ws[3]) * (1.0f / (float)NPIX);
}

extern "C" void kernel_launch(void* const* d_in, const int* in_sizes, int n_in,
                              void* d_out, int out_size, void* d_ws,
                              size_t ws_size, hipStream_t stream) {
  const float* pred = (const float*)d_in[0];
  const float* targ = (const float*)d_in[1];
  float* out = (float*)d_out;
  float* partial = (float*)d_ws;  // NROWS f32 = 6 KB

  fused_pass<<<B * SPLITS, NTHR, 0, stream>>>(pred, targ, partial);
  reduce_pass<<<1, 256, 0, stream>>>(partial, out);
}